// Round 16
// baseline (59.174 us; speedup 1.0000x reference)
//
#include <hip/hip_runtime.h>
#include <hip/hip_fp16.h>
#include <math.h>

#define N_RADIAL 8
#define N_PSEUDO 4
#define EMB_DIM 32
#define CUTOFF 5.0f
#define WIDTH 0.5f
#define SQRT3_4PI 0.48860251190291992f   /* sqrt(3/(4*pi)) */
#define INV_SQRT2 0.70710678118654752f
#define PI_F 3.14159265358979323846f

#define SLICE_SHIFT 8
#define SLICE_SZ 256            /* atoms per slice */
#define MAX_NSLICE 1024         /* LDS histogram capacity (A <= 262k) */
#define SCAT_EPB 2048           /* edges per block, scatter pass */
#define SCAT_THREADS 512        /* 8-wave blocks: 4/CU resident (1024t caps ~50%) */
#define SCAT_ITER (SCAT_EPB / SCAT_THREADS)   /* 4: register payload stash */
#define ACC_THREADS 1024        /* accum grid < #CU: 1 block/CU, want max waves */
#define MAX_SPEC_WORDS 4096     /* 2-bit packed species: supports A <= 65536 */

/* Fixed-point packing (proven R6/R13): q=2^-13, bias 16.
   word = [count:12 | e_hi:26 | e_lo:26]; per-edge add non-negative in every
   field -> no cross-field carries; capacity 4096 edges/atom. */
#define Q_INV 8192.0f
#define Q 1.220703125e-4
#define BIAS_ENC 131072.0f
#define ENC_MAX 262143.0f
#define FIELD_MASK 0x3FFFFFFULL

// ---------------------------------------------------------------------------
// Init: block 0 builds G[tc][tn][n][k] (k=0,1) + per-slice cursors (s*cap);
// all blocks pack species into 2-bit words (16 atoms per u32).
// ---------------------------------------------------------------------------
__global__ void init_kernel(const float* __restrict__ W_species, // (4,4)
                            const float* __restrict__ Emb,       // (4,32)
                            const float* __restrict__ Wc,        // (32,3)
                            const int*   __restrict__ species,   // (A,)
                            float* __restrict__ G,
                            unsigned int* __restrict__ cursor,
                            unsigned int* __restrict__ spec_packed,
                            int A, int nslice, int cap, int words) {
    int tid = blockIdx.x * blockDim.x + threadIdx.x;

    if (blockIdx.x == 0) {
        int i = threadIdx.x;
        if (i < 256) {
            int k  = i & 1;
            int n  = (i >> 1) & 7;
            int tn = (i >> 4) & 3;
            int tc = i >> 6;
            float acc = 0.0f;
            #pragma unroll
            for (int q = 0; q < N_PSEUDO; ++q) {
                int d = n * N_PSEUDO + q;
                acc += W_species[tn * N_PSEUDO + q] * Emb[tc * EMB_DIM + d] * Wc[d * 3 + k];
            }
            G[i] = acc;
        }
        for (int s = i; s < nslice; s += (int)blockDim.x)
            cursor[s] = (unsigned int)(s * cap);
    }

    for (int w = tid; w < words; w += (int)(gridDim.x * blockDim.x)) {
        unsigned int v = 0;
        int base = w * 16;
        #pragma unroll
        for (int j = 0; j < 16; ++j) {
            int a = base + j;
            if (a < A) v |= ((unsigned int)species[a] & 3u) << (2 * j);
        }
        spec_packed[w] = v;
    }
}

// ---------------------------------------------------------------------------
// Per-edge math, native trig (theta < pi: no range reduction needed).
// pr[j] = Y[m]*s[k] m-major: (Y0s0,Y0s1,Y1s0,Y1s1,Y2s0,Y2s1)
// ---------------------------------------------------------------------------
__device__ __forceinline__ bool edge_products(float vx, float vy, float vz,
                                              const float* __restrict__ Gp,
                                              float pr[6]) {
    float r = sqrtf(vx * vx + vy * vy + vz * vz);
    if (r >= CUTOFF) return false;

    float rinv = 1.0f / (r + 1e-10f);

    float t = fminf(fmaxf((r - (CUTOFF - WIDTH)) * (1.0f / WIDTH), 0.0f), 1.0f);
    float fcut = 0.5f * (1.0f + __cosf(PI_F * t));

    float theta = (PI_F / CUTOFF) * r;
    float s1 = __sinf(theta);
    float c1 = __cosf(theta);
    float twoc  = 2.0f * c1;
    float sn_m1 = 0.0f;
    float sn    = s1;

    float s0 = 0.0f, s1a = 0.0f;
    #pragma unroll
    for (int n = 0; n < N_RADIAL; ++n) {
        s0  = fmaf(sn, Gp[n * 2 + 0], s0);
        s1a = fmaf(sn, Gp[n * 2 + 1], s1a);
        float nxt = twoc * sn - sn_m1;
        sn_m1 = sn;
        sn = nxt;
    }
    float coef = rinv * fcut;
    s0 *= coef; s1a *= coef;

    float Y0 = SQRT3_4PI * vy * rinv;
    float Y1 = SQRT3_4PI * vz * rinv;
    float Y2 = SQRT3_4PI * vx * rinv;

    pr[0] = Y0 * s0; pr[1] = Y0 * s1a;
    pr[2] = Y1 * s0; pr[3] = Y1 * s1a;
    pr[4] = Y2 * s0; pr[5] = Y2 * s1a;
    return true;
}

// ---------------------------------------------------------------------------
// Scatter: species lookups from a 2-bit LDS table, register payload stash,
// one cursor reservation per touched slice, bounds-checked placement.
// 512-thread blocks (R15 finding: 1024t workgroups cap at ~50% occupancy;
// grid must exceed ~500k threads to fill the chip).
// ---------------------------------------------------------------------------
template <bool LDSSPEC>
__global__ __launch_bounds__(SCAT_THREADS)
void scatter_kernel(const float* __restrict__ vecs,
                    const int*   __restrict__ centers,
                    const int*   __restrict__ neighbors,
                    const unsigned int* __restrict__ spec_packed,
                    unsigned int* __restrict__ cursor,
                    unsigned long long* __restrict__ payload, // 8B per entry
                    int E, int nslice, int cap, int words) {
    __shared__ unsigned int hist[MAX_NSLICE];
    __shared__ unsigned int spec[LDSSPEC ? MAX_SPEC_WORDS : 1];

    for (int i = threadIdx.x; i < nslice; i += blockDim.x) hist[i] = 0u;
    if constexpr (LDSSPEC) {
        for (int i = threadIdx.x; i < words; i += blockDim.x)
            spec[i] = spec_packed[i];
    }
    __syncthreads();

    int beg = blockIdx.x * SCAT_EPB;
    int end = min(beg + SCAT_EPB, E);

    unsigned long long word[SCAT_ITER];
    int sl[SCAT_ITER];

    // single read pass: predicate on r^2 (no sqrt), encode, LDS count
    #pragma unroll
    for (int k = 0; k < SCAT_ITER; ++k) {
        sl[k] = -1;
        word[k] = 0;
        int e = beg + k * SCAT_THREADS + (int)threadIdx.x;
        if (e < end) {
            float vx = vecs[3 * e + 0], vy = vecs[3 * e + 1], vz = vecs[3 * e + 2];
            float r2 = vx * vx + vy * vy + vz * vz;
            if (r2 < CUTOFF * CUTOFF) {
                int c  = centers[e];
                int nb = neighbors[e];
                unsigned int tc, tn;
                if constexpr (LDSSPEC) {
                    tc = (spec[c >> 4]  >> ((c & 15) << 1)) & 3u;
                    tn = (spec[nb >> 4] >> ((nb & 15) << 1)) & 3u;
                } else {
                    tc = (spec_packed[c >> 4]  >> ((c & 15) << 1)) & 3u;
                    tn = (spec_packed[nb >> 4] >> ((nb & 15) << 1)) & 3u;
                }
                unsigned int meta = (unsigned int)(c & (SLICE_SZ - 1)) | (tc << 8) | (tn << 10);
                unsigned int hx = (unsigned int)__half_as_ushort(__float2half(vx));
                unsigned int hy = (unsigned int)__half_as_ushort(__float2half(vy));
                unsigned int hz = (unsigned int)__half_as_ushort(__float2half(vz));
                unsigned int lo = hx | (hy << 16);
                unsigned int hi = hz | (meta << 16);
                word[k] = ((unsigned long long)hi << 32) | lo;
                sl[k] = c >> SLICE_SHIFT;
                atomicAdd(&hist[sl[k]], 1u);
            }
        }
    }
    __syncthreads();

    // reserve global ranges; hist[s] becomes this block's running cursor
    for (int s = threadIdx.x; s < nslice; s += (int)blockDim.x) {
        unsigned int c = hist[s];
        hist[s] = c ? atomicAdd(&cursor[s], c) : 0u;
    }
    __syncthreads();

    // placement from registers; bounds check guards slice-capacity overflow
    // (cap = mean + 8*sigma: overflow prob ~1e-13/slice)
    #pragma unroll
    for (int k = 0; k < SCAT_ITER; ++k) {
        if (sl[k] >= 0) {
            unsigned int pos = atomicAdd(&hist[sl[k]], 1u);
            if (pos < (unsigned int)((sl[k] + 1) * cap))
                payload[pos] = word[k];
        }
    }
}

// ---------------------------------------------------------------------------
// Accum: one block per slice (196 blocks < 256 CUs -> each block owns a CU;
// 1024 threads = max waves on that CU). Contiguous 8B reads, f16 decode,
// native-trig math, 3 native u64 LDS atomics per edge (ds_add_u64; f32 LDS
// atomicAdd is a slow CAS path — R13), fixed-point decode + cross product.
// ---------------------------------------------------------------------------
__global__ __launch_bounds__(ACC_THREADS)
void accum_kernel(const unsigned long long* __restrict__ payload,
                  const unsigned int* __restrict__ cursor,   // final = packed end
                  const float* __restrict__ G,
                  float* __restrict__ out, int A, int cap) {
    __shared__ float Gs[256];
    __shared__ unsigned long long acc64[SLICE_SZ * 3];
    int s = blockIdx.x;

    if (threadIdx.x < 256) Gs[threadIdx.x] = G[threadIdx.x];
    for (int i = threadIdx.x; i < SLICE_SZ * 3; i += blockDim.x) acc64[i] = 0ull;
    __syncthreads();

    unsigned int beg = (unsigned int)(s * cap);
    unsigned int end = min(cursor[s], (unsigned int)((s + 1) * cap));
    for (unsigned int i = beg + threadIdx.x; i < end; i += blockDim.x) {
        unsigned long long w = payload[i];
        unsigned int lo = (unsigned int)w;
        unsigned int hi = (unsigned int)(w >> 32);
        float vx = __half2float(__ushort_as_half((unsigned short)(lo & 0xffffu)));
        float vy = __half2float(__ushort_as_half((unsigned short)(lo >> 16)));
        float vz = __half2float(__ushort_as_half((unsigned short)(hi & 0xffffu)));
        unsigned int meta = hi >> 16;
        int lid = (int)(meta & (SLICE_SZ - 1));
        int tc  = (int)((meta >> 8) & 3);
        int tn  = (int)((meta >> 10) & 3);
        const float* Gp = &Gs[((tc * 4 + tn) * 8) * 2];

        float pr[6];
        if (!edge_products(vx, vy, vz, Gp, pr)) continue;  // f16-boundary: fcut~0

        unsigned long long* ap = &acc64[lid * 3];
        #pragma unroll
        for (int j = 0; j < 3; ++j) {
            float el = fminf(fmaxf(fmaf(pr[2 * j + 0], Q_INV, BIAS_ENC) + 0.5f, 0.0f), ENC_MAX);
            float eh = fminf(fmaxf(fmaf(pr[2 * j + 1], Q_INV, BIAS_ENC) + 0.5f, 0.0f), ENC_MAX);
            unsigned long long wrd = (1ULL << 52)
                                   | ((unsigned long long)(unsigned int)eh << 26)
                                   | (unsigned long long)(unsigned int)el;
            atomicAdd(ap + j, wrd);
        }
    }
    __syncthreads();

    for (int lid = threadIdx.x; lid < SLICE_SZ; lid += (int)blockDim.x) {
        int a = s * SLICE_SZ + lid;
        if (a >= A) break;
        const unsigned long long* wv = &acc64[lid * 3];
        float v[6];
        #pragma unroll
        for (int j = 0; j < 3; ++j) {
            unsigned long long x = wv[j];
            float n = (float)(unsigned int)(x >> 52);
            v[2 * j + 0] = (float)((double)(x & FIELD_MASK)         * Q) - n * 16.0f;
            v[2 * j + 1] = (float)((double)((x >> 26) & FIELD_MASK) * Q) - n * 16.0f;
        }

        float a0 = v[0], b0 = v[1];   // m=0 (y)
        float a1 = v[2], b1 = v[3];   // m=1 (z)
        float a2 = v[4], b2 = v[5];   // m=2 (x)

        float c0 = (a1 * b2 - a2 * b1) * INV_SQRT2;
        float c1 = (a2 * b0 - a0 * b2) * INV_SQRT2;
        float c2 = (a0 * b1 - a1 * b0) * INV_SQRT2;

        float* o = out + (size_t)a * 9;
        o[0] = a0; o[1] = b0; o[2] = c0;
        o[3] = a1; o[4] = b1; o[5] = c1;
        o[6] = a2; o[7] = b2; o[8] = c2;
    }
}

// ===========================================================================
// Fallback path (Round 6): packed fixed-point u64 global atomics. Used only
// if the workspace can't hold the fixed-capacity payload.
// ===========================================================================
__global__ void edge_kernel_fb(const float* __restrict__ vecs,
                               const int* __restrict__ centers,
                               const int* __restrict__ neighbors,
                               const int* __restrict__ species,
                               const float* __restrict__ G,
                               unsigned long long* __restrict__ vacc, int E) {
    __shared__ float Gs[256];
    Gs[threadIdx.x] = G[threadIdx.x];
    __syncthreads();

    int e = blockIdx.x * blockDim.x + threadIdx.x;
    if (e >= E) return;

    float vx = vecs[3 * e + 0], vy = vecs[3 * e + 1], vz = vecs[3 * e + 2];
    int c = centers[e];
    int tc = species[c];
    int tn = species[neighbors[e]];
    const float* Gp = &Gs[((tc * 4 + tn) * 8) * 2];

    float pr[6];
    if (!edge_products(vx, vy, vz, Gp, pr)) return;

    unsigned long long* base = vacc + (size_t)c * 4;
    #pragma unroll
    for (int j = 0; j < 3; ++j) {
        float el = fminf(fmaxf(fmaf(pr[2 * j + 0], Q_INV, BIAS_ENC) + 0.5f, 0.0f), ENC_MAX);
        float eh = fminf(fmaxf(fmaf(pr[2 * j + 1], Q_INV, BIAS_ENC) + 0.5f, 0.0f), ENC_MAX);
        unsigned long long w = (1ULL << 52)
                             | ((unsigned long long)(unsigned int)eh << 26)
                             | (unsigned long long)(unsigned int)el;
        atomicAdd(base + j, w);
    }
}

__global__ void finalize_fb(const unsigned long long* __restrict__ vacc,
                            float* __restrict__ out, int A) {
    int a = blockIdx.x * blockDim.x + threadIdx.x;
    if (a >= A) return;

    const unsigned long long* w = vacc + (size_t)a * 4;
    double v[6];
    #pragma unroll
    for (int j = 0; j < 3; ++j) {
        unsigned long long x = w[j];
        double n = (double)(x >> 52);
        v[2 * j + 0] = (double)(x & FIELD_MASK)         * (double)Q - n * 16.0;
        v[2 * j + 1] = (double)((x >> 26) & FIELD_MASK) * (double)Q - n * 16.0;
    }
    float a0 = (float)v[0], b0 = (float)v[1];
    float a1 = (float)v[2], b1 = (float)v[3];
    float a2 = (float)v[4], b2 = (float)v[5];
    float c0 = (a1 * b2 - a2 * b1) * INV_SQRT2;
    float c1 = (a2 * b0 - a0 * b2) * INV_SQRT2;
    float c2 = (a0 * b1 - a1 * b0) * INV_SQRT2;
    float* o = out + (size_t)a * 9;
    o[0] = a0; o[1] = b0; o[2] = c0;
    o[3] = a1; o[4] = b1; o[5] = c1;
    o[6] = a2; o[7] = b2; o[8] = c2;
}

extern "C" void kernel_launch(void* const* d_in, const int* in_sizes, int n_in,
                              void* d_out, int out_size, void* d_ws, size_t ws_size,
                              hipStream_t stream) {
    const float* vecs      = (const float*)d_in[0];
    const float* W_species = (const float*)d_in[1];
    const float* Emb       = (const float*)d_in[2];
    const float* Wc        = (const float*)d_in[3];
    const int*   centers   = (const int*)d_in[4];
    const int*   neighbors = (const int*)d_in[5];
    const int*   species   = (const int*)d_in[6];

    int E = in_sizes[0] / 3;
    int A = in_sizes[6];

    int nslice = (A + SLICE_SZ - 1) / SLICE_SZ;
    int words  = (A + 15) / 16;

    // Fixed per-slice capacity: mean + 8*sigma (multinomial tail ~1e-13),
    // rounded up to 64. Counts ALL edges (7% above passing: extra slack).
    double mean = (double)E / (double)nslice;
    int cap = (int)((mean + 8.0 * sqrt(mean) + 63.0) / 64.0) * 64;

    // Workspace: payload (nslice*cap u64) | cursor | G | spec_packed
    size_t payloadBytes = (size_t)nslice * (size_t)cap * 8;
    size_t metaBytes    = ((size_t)nslice + 256 + (size_t)words) * 4 + 256;
    bool sort_path = (nslice <= MAX_NSLICE) && (ws_size >= payloadBytes + metaBytes);

    if (sort_path) {
        unsigned long long* payload = (unsigned long long*)d_ws;
        unsigned int* cursor = (unsigned int*)((char*)d_ws + payloadBytes);
        float*        G      = (float*)(cursor + nslice);
        unsigned int* spec_packed = (unsigned int*)(G + 256);

        int nbi = max(1, (words + 1023) / 1024);
        init_kernel<<<nbi, 1024, 0, stream>>>(W_species, Emb, Wc, species,
                                              G, cursor, spec_packed,
                                              A, nslice, cap, words);
        int nbs = (E + SCAT_EPB - 1) / SCAT_EPB;
        if (words <= MAX_SPEC_WORDS) {
            scatter_kernel<true><<<nbs, SCAT_THREADS, 0, stream>>>(
                vecs, centers, neighbors, spec_packed, cursor, payload,
                E, nslice, cap, words);
        } else {
            scatter_kernel<false><<<nbs, SCAT_THREADS, 0, stream>>>(
                vecs, centers, neighbors, spec_packed, cursor, payload,
                E, nslice, cap, words);
        }
        accum_kernel<<<nslice, ACC_THREADS, 0, stream>>>(
            payload, cursor, G, (float*)d_out, A, cap);
    } else {
        unsigned long long* vacc = (unsigned long long*)d_ws;  // (A,4)
        float* G = (float*)(vacc + (size_t)A * 4);
        unsigned int* cursor_dummy = (unsigned int*)(G + 256);
        (void)hipMemsetAsync(vacc, 0, (size_t)A * 4 * sizeof(unsigned long long), stream);
        init_kernel<<<1, 1024, 0, stream>>>(W_species, Emb, Wc, species,
                                            G, cursor_dummy, cursor_dummy,
                                            0, 0, 0, 0);
        const int threads = 256;
        edge_kernel_fb<<<(E + threads - 1) / threads, threads, 0, stream>>>(
            vecs, centers, neighbors, species, G, vacc, E);
        finalize_fb<<<(A + threads - 1) / threads, threads, 0, stream>>>(
            vacc, (float*)d_out, A);
    }
}

// Round 17
// 47.975 us; speedup vs baseline: 1.2334x; 1.2334x over previous
//
#include <hip/hip_runtime.h>
#include <hip/hip_fp16.h>
#include <math.h>

#define N_RADIAL 8
#define N_PSEUDO 4
#define EMB_DIM 32
#define CUTOFF 5.0f
#define WIDTH 0.5f
#define SQRT3_4PI 0.48860251190291992f   /* sqrt(3/(4*pi)) */
#define INV_SQRT2 0.70710678118654752f
#define PI_F 3.14159265358979323846f

#define SLICE_SHIFT 8
#define SLICE_SZ 256            /* atoms per slice */
#define MAX_NSLICE 1024         /* LDS histogram capacity (A <= 262k) */
#define SCAT_EPB 8192           /* edges per block (R15-proven: few blocks, few reservations) */
#define SCAT_THREADS 1024
#define SCAT_GROUPS 2           /* 2 groups x 4 edges x 1024 threads = 8192 */
#define ACC_THREADS 1024
#define MAX_SPEC_WORDS 4096     /* 2-bit packed species: supports A <= 65536 */

/* Fixed-point packing (proven R6/R13): q=2^-13, bias 16.
   word = [count:12 | e_hi:26 | e_lo:26]; per-edge add non-negative in every
   field -> no cross-field carries; capacity 4096 edges/atom. */
#define Q_INV 8192.0f
#define Q 1.220703125e-4
#define BIAS_ENC 131072.0f
#define ENC_MAX 262143.0f
#define FIELD_MASK 0x3FFFFFFULL

// ---------------------------------------------------------------------------
// Init: block 0 builds G[tc][tn][n][k] (k=0,1) + per-slice cursors (s*cap);
// all blocks pack species into 2-bit words (16 atoms per u32).
// ---------------------------------------------------------------------------
__global__ void init_kernel(const float* __restrict__ W_species, // (4,4)
                            const float* __restrict__ Emb,       // (4,32)
                            const float* __restrict__ Wc,        // (32,3)
                            const int*   __restrict__ species,   // (A,)
                            float* __restrict__ G,
                            unsigned int* __restrict__ cursor,
                            unsigned int* __restrict__ spec_packed,
                            int A, int nslice, int cap, int words) {
    int tid = blockIdx.x * blockDim.x + threadIdx.x;

    if (blockIdx.x == 0) {
        int i = threadIdx.x;
        if (i < 256) {
            int k  = i & 1;
            int n  = (i >> 1) & 7;
            int tn = (i >> 4) & 3;
            int tc = i >> 6;
            float acc = 0.0f;
            #pragma unroll
            for (int q = 0; q < N_PSEUDO; ++q) {
                int d = n * N_PSEUDO + q;
                acc += W_species[tn * N_PSEUDO + q] * Emb[tc * EMB_DIM + d] * Wc[d * 3 + k];
            }
            G[i] = acc;
        }
        for (int s = i; s < nslice; s += (int)blockDim.x)
            cursor[s] = (unsigned int)(s * cap);
    }

    for (int w = tid; w < words; w += (int)(gridDim.x * blockDim.x)) {
        unsigned int v = 0;
        int base = w * 16;
        #pragma unroll
        for (int j = 0; j < 16; ++j) {
            int a = base + j;
            if (a < A) v |= ((unsigned int)species[a] & 3u) << (2 * j);
        }
        spec_packed[w] = v;
    }
}

// ---------------------------------------------------------------------------
// Per-edge math, native trig (theta < pi: no range reduction needed).
// pr[j] = Y[m]*s[k] m-major: (Y0s0,Y0s1,Y1s0,Y1s1,Y2s0,Y2s1)
// ---------------------------------------------------------------------------
__device__ __forceinline__ bool edge_products(float vx, float vy, float vz,
                                              const float* __restrict__ Gp,
                                              float pr[6]) {
    float r = sqrtf(vx * vx + vy * vy + vz * vz);
    if (r >= CUTOFF) return false;

    float rinv = 1.0f / (r + 1e-10f);

    float t = fminf(fmaxf((r - (CUTOFF - WIDTH)) * (1.0f / WIDTH), 0.0f), 1.0f);
    float fcut = 0.5f * (1.0f + __cosf(PI_F * t));

    float theta = (PI_F / CUTOFF) * r;
    float s1 = __sinf(theta);
    float c1 = __cosf(theta);
    float twoc  = 2.0f * c1;
    float sn_m1 = 0.0f;
    float sn    = s1;

    float s0 = 0.0f, s1a = 0.0f;
    #pragma unroll
    for (int n = 0; n < N_RADIAL; ++n) {
        s0  = fmaf(sn, Gp[n * 2 + 0], s0);
        s1a = fmaf(sn, Gp[n * 2 + 1], s1a);
        float nxt = twoc * sn - sn_m1;
        sn_m1 = sn;
        sn = nxt;
    }
    float coef = rinv * fcut;
    s0 *= coef; s1a *= coef;

    float Y0 = SQRT3_4PI * vy * rinv;
    float Y1 = SQRT3_4PI * vz * rinv;
    float Y2 = SQRT3_4PI * vx * rinv;

    pr[0] = Y0 * s0; pr[1] = Y0 * s1a;
    pr[2] = Y1 * s0; pr[3] = Y1 * s1a;
    pr[4] = Y2 * s0; pr[5] = Y2 * s1a;
    return true;
}

// ---------------------------------------------------------------------------
// Encode one edge into the 8B payload word + slice id. Static inlining only.
// ---------------------------------------------------------------------------
__device__ __forceinline__ void encode_edge(float vx, float vy, float vz,
                                            int c, int nb,
                                            const unsigned int* __restrict__ spec,
                                            unsigned long long& word, int& sl) {
    float r2 = vx * vx + vy * vy + vz * vz;
    if (r2 < CUTOFF * CUTOFF) {
        unsigned int tc = (spec[c >> 4]  >> ((c & 15) << 1)) & 3u;
        unsigned int tn = (spec[nb >> 4] >> ((nb & 15) << 1)) & 3u;
        unsigned int meta = (unsigned int)(c & (SLICE_SZ - 1)) | (tc << 8) | (tn << 10);
        unsigned int hx = (unsigned int)__half_as_ushort(__float2half(vx));
        unsigned int hy = (unsigned int)__half_as_ushort(__float2half(vy));
        unsigned int hz = (unsigned int)__half_as_ushort(__float2half(vz));
        word = ((unsigned long long)(hz | (meta << 16)) << 32)
             | (unsigned long long)(hx | (hy << 16));
        sl = c >> SLICE_SHIFT;
    }
}

// ---------------------------------------------------------------------------
// Scatter (R15 shape: 1024t, EPB 8192, 245 blocks, ~48k reservations) with
// VECTORIZED edge reads: each thread owns 4 consecutive edges per group ->
// 3x float4 (vecs) + int4 (centers) + int4 (neighbors) = 5 vector loads
// instead of 20 scalar dword loads (G13; R16 showed occupancy isn't the
// lever, so cut memory-op issue count instead).
// ---------------------------------------------------------------------------
__global__ __launch_bounds__(SCAT_THREADS)
void scatter_kernel(const float* __restrict__ vecs,
                    const int*   __restrict__ centers,
                    const int*   __restrict__ neighbors,
                    const unsigned int* __restrict__ spec_packed,
                    unsigned int* __restrict__ cursor,
                    unsigned long long* __restrict__ payload, // 8B per entry
                    int E, int nslice, int cap, int words) {
    __shared__ unsigned int hist[MAX_NSLICE];
    __shared__ unsigned int spec[MAX_SPEC_WORDS];

    for (int i = threadIdx.x; i < nslice; i += blockDim.x) hist[i] = 0u;
    for (int i = threadIdx.x; i < words; i += blockDim.x) spec[i] = spec_packed[i];
    __syncthreads();

    const int beg = blockIdx.x * SCAT_EPB;

    unsigned long long word[SCAT_GROUPS * 4];
    int sl[SCAT_GROUPS * 4];

    // read + encode + LDS count; all indexing static after unroll
    #pragma unroll
    for (int g = 0; g < SCAT_GROUPS; ++g) {
        int e0 = beg + g * (SCAT_THREADS * 4) + (int)threadIdx.x * 4;
        #pragma unroll
        for (int j = 0; j < 4; ++j) { sl[g * 4 + j] = -1; word[g * 4 + j] = 0; }

        if (e0 + 4 <= E) {
            const float4* vp = (const float4*)vecs + ((e0 * 3) >> 2);
            float4 v0 = vp[0], v1 = vp[1], v2 = vp[2];
            int4 c4 = ((const int4*)centers)[e0 >> 2];
            int4 n4 = ((const int4*)neighbors)[e0 >> 2];

            encode_edge(v0.x, v0.y, v0.z, c4.x, n4.x, spec, word[g*4+0], sl[g*4+0]);
            encode_edge(v0.w, v1.x, v1.y, c4.y, n4.y, spec, word[g*4+1], sl[g*4+1]);
            encode_edge(v1.z, v1.w, v2.x, c4.z, n4.z, spec, word[g*4+2], sl[g*4+2]);
            encode_edge(v2.y, v2.z, v2.w, c4.w, n4.w, spec, word[g*4+3], sl[g*4+3]);
        } else {
            #pragma unroll
            for (int j = 0; j < 4; ++j) {
                int e = e0 + j;
                if (e < E) {
                    encode_edge(vecs[3*e], vecs[3*e+1], vecs[3*e+2],
                                centers[e], neighbors[e], spec,
                                word[g*4+j], sl[g*4+j]);
                }
            }
        }

        #pragma unroll
        for (int j = 0; j < 4; ++j)
            if (sl[g * 4 + j] >= 0) atomicAdd(&hist[sl[g * 4 + j]], 1u);
    }
    __syncthreads();

    // reserve global ranges; hist[s] becomes this block's running cursor
    for (int s = threadIdx.x; s < nslice; s += (int)blockDim.x) {
        unsigned int c = hist[s];
        hist[s] = c ? atomicAdd(&cursor[s], c) : 0u;
    }
    __syncthreads();

    // placement from registers; bounds check guards slice-capacity overflow
    #pragma unroll
    for (int k = 0; k < SCAT_GROUPS * 4; ++k) {
        if (sl[k] >= 0) {
            unsigned int pos = atomicAdd(&hist[sl[k]], 1u);
            if (pos < (unsigned int)((sl[k] + 1) * cap))
                payload[pos] = word[k];
        }
    }
}

// ---------------------------------------------------------------------------
// Accum: one block per slice. Contiguous 8B reads, f16 decode, native-trig
// math, 3 native u64 LDS atomics per edge (ds_add_u64; f32 LDS atomicAdd is
// a slow CAS path — R13), fixed-point decode + cross product epilogue.
// ---------------------------------------------------------------------------
__global__ __launch_bounds__(ACC_THREADS)
void accum_kernel(const unsigned long long* __restrict__ payload,
                  const unsigned int* __restrict__ cursor,   // final = packed end
                  const float* __restrict__ G,
                  float* __restrict__ out, int A, int cap) {
    __shared__ float Gs[256];
    __shared__ unsigned long long acc64[SLICE_SZ * 3];
    int s = blockIdx.x;

    if (threadIdx.x < 256) Gs[threadIdx.x] = G[threadIdx.x];
    for (int i = threadIdx.x; i < SLICE_SZ * 3; i += blockDim.x) acc64[i] = 0ull;
    __syncthreads();

    unsigned int beg = (unsigned int)(s * cap);
    unsigned int end = min(cursor[s], (unsigned int)((s + 1) * cap));
    for (unsigned int i = beg + threadIdx.x; i < end; i += blockDim.x) {
        unsigned long long w = payload[i];
        unsigned int lo = (unsigned int)w;
        unsigned int hi = (unsigned int)(w >> 32);
        float vx = __half2float(__ushort_as_half((unsigned short)(lo & 0xffffu)));
        float vy = __half2float(__ushort_as_half((unsigned short)(lo >> 16)));
        float vz = __half2float(__ushort_as_half((unsigned short)(hi & 0xffffu)));
        unsigned int meta = hi >> 16;
        int lid = (int)(meta & (SLICE_SZ - 1));
        int tc  = (int)((meta >> 8) & 3);
        int tn  = (int)((meta >> 10) & 3);
        const float* Gp = &Gs[((tc * 4 + tn) * 8) * 2];

        float pr[6];
        if (!edge_products(vx, vy, vz, Gp, pr)) continue;  // f16-boundary: fcut~0

        unsigned long long* ap = &acc64[lid * 3];
        #pragma unroll
        for (int j = 0; j < 3; ++j) {
            float el = fminf(fmaxf(fmaf(pr[2 * j + 0], Q_INV, BIAS_ENC) + 0.5f, 0.0f), ENC_MAX);
            float eh = fminf(fmaxf(fmaf(pr[2 * j + 1], Q_INV, BIAS_ENC) + 0.5f, 0.0f), ENC_MAX);
            unsigned long long wrd = (1ULL << 52)
                                   | ((unsigned long long)(unsigned int)eh << 26)
                                   | (unsigned long long)(unsigned int)el;
            atomicAdd(ap + j, wrd);
        }
    }
    __syncthreads();

    for (int lid = threadIdx.x; lid < SLICE_SZ; lid += (int)blockDim.x) {
        int a = s * SLICE_SZ + lid;
        if (a >= A) break;
        const unsigned long long* wv = &acc64[lid * 3];
        float v[6];
        #pragma unroll
        for (int j = 0; j < 3; ++j) {
            unsigned long long x = wv[j];
            float n = (float)(unsigned int)(x >> 52);
            v[2 * j + 0] = (float)((double)(x & FIELD_MASK)         * Q) - n * 16.0f;
            v[2 * j + 1] = (float)((double)((x >> 26) & FIELD_MASK) * Q) - n * 16.0f;
        }

        float a0 = v[0], b0 = v[1];   // m=0 (y)
        float a1 = v[2], b1 = v[3];   // m=1 (z)
        float a2 = v[4], b2 = v[5];   // m=2 (x)

        float c0 = (a1 * b2 - a2 * b1) * INV_SQRT2;
        float c1 = (a2 * b0 - a0 * b2) * INV_SQRT2;
        float c2 = (a0 * b1 - a1 * b0) * INV_SQRT2;

        float* o = out + (size_t)a * 9;
        o[0] = a0; o[1] = b0; o[2] = c0;
        o[3] = a1; o[4] = b1; o[5] = c1;
        o[6] = a2; o[7] = b2; o[8] = c2;
    }
}

// ===========================================================================
// Fallback path (Round 6): packed fixed-point u64 global atomics. Used only
// if the workspace can't hold the fixed-capacity payload.
// ===========================================================================
__global__ void edge_kernel_fb(const float* __restrict__ vecs,
                               const int* __restrict__ centers,
                               const int* __restrict__ neighbors,
                               const int* __restrict__ species,
                               const float* __restrict__ G,
                               unsigned long long* __restrict__ vacc, int E) {
    __shared__ float Gs[256];
    Gs[threadIdx.x] = G[threadIdx.x];
    __syncthreads();

    int e = blockIdx.x * blockDim.x + threadIdx.x;
    if (e >= E) return;

    float vx = vecs[3 * e + 0], vy = vecs[3 * e + 1], vz = vecs[3 * e + 2];
    int c = centers[e];
    int tc = species[c];
    int tn = species[neighbors[e]];
    const float* Gp = &Gs[((tc * 4 + tn) * 8) * 2];

    float pr[6];
    if (!edge_products(vx, vy, vz, Gp, pr)) return;

    unsigned long long* base = vacc + (size_t)c * 4;
    #pragma unroll
    for (int j = 0; j < 3; ++j) {
        float el = fminf(fmaxf(fmaf(pr[2 * j + 0], Q_INV, BIAS_ENC) + 0.5f, 0.0f), ENC_MAX);
        float eh = fminf(fmaxf(fmaf(pr[2 * j + 1], Q_INV, BIAS_ENC) + 0.5f, 0.0f), ENC_MAX);
        unsigned long long w = (1ULL << 52)
                             | ((unsigned long long)(unsigned int)eh << 26)
                             | (unsigned long long)(unsigned int)el;
        atomicAdd(base + j, w);
    }
}

__global__ void finalize_fb(const unsigned long long* __restrict__ vacc,
                            float* __restrict__ out, int A) {
    int a = blockIdx.x * blockDim.x + threadIdx.x;
    if (a >= A) return;

    const unsigned long long* w = vacc + (size_t)a * 4;
    double v[6];
    #pragma unroll
    for (int j = 0; j < 3; ++j) {
        unsigned long long x = w[j];
        double n = (double)(x >> 52);
        v[2 * j + 0] = (double)(x & FIELD_MASK)         * (double)Q - n * 16.0;
        v[2 * j + 1] = (double)((x >> 26) & FIELD_MASK) * (double)Q - n * 16.0;
    }
    float a0 = (float)v[0], b0 = (float)v[1];
    float a1 = (float)v[2], b1 = (float)v[3];
    float a2 = (float)v[4], b2 = (float)v[5];
    float c0 = (a1 * b2 - a2 * b1) * INV_SQRT2;
    float c1 = (a2 * b0 - a0 * b2) * INV_SQRT2;
    float c2 = (a0 * b1 - a1 * b0) * INV_SQRT2;
    float* o = out + (size_t)a * 9;
    o[0] = a0; o[1] = b0; o[2] = c0;
    o[3] = a1; o[4] = b1; o[5] = c1;
    o[6] = a2; o[7] = b2; o[8] = c2;
}

extern "C" void kernel_launch(void* const* d_in, const int* in_sizes, int n_in,
                              void* d_out, int out_size, void* d_ws, size_t ws_size,
                              hipStream_t stream) {
    const float* vecs      = (const float*)d_in[0];
    const float* W_species = (const float*)d_in[1];
    const float* Emb       = (const float*)d_in[2];
    const float* Wc        = (const float*)d_in[3];
    const int*   centers   = (const int*)d_in[4];
    const int*   neighbors = (const int*)d_in[5];
    const int*   species   = (const int*)d_in[6];

    int E = in_sizes[0] / 3;
    int A = in_sizes[6];

    int nslice = (A + SLICE_SZ - 1) / SLICE_SZ;
    int words  = (A + 15) / 16;

    // Fixed per-slice capacity: mean + 8*sigma (multinomial tail ~1e-13),
    // rounded up to 64. Counts ALL edges (7% above passing: extra slack).
    double mean = (double)E / (double)nslice;
    int cap = (int)((mean + 8.0 * sqrt(mean) + 63.0) / 64.0) * 64;

    // Workspace: payload (nslice*cap u64) | cursor | G | spec_packed
    size_t payloadBytes = (size_t)nslice * (size_t)cap * 8;
    size_t metaBytes    = ((size_t)nslice + 256 + (size_t)words) * 4 + 256;
    bool sort_path = (nslice <= MAX_NSLICE) && (words <= MAX_SPEC_WORDS) &&
                     (ws_size >= payloadBytes + metaBytes);

    if (sort_path) {
        unsigned long long* payload = (unsigned long long*)d_ws;
        unsigned int* cursor = (unsigned int*)((char*)d_ws + payloadBytes);
        float*        G      = (float*)(cursor + nslice);
        unsigned int* spec_packed = (unsigned int*)(G + 256);

        int nbi = max(1, (words + 1023) / 1024);
        init_kernel<<<nbi, 1024, 0, stream>>>(W_species, Emb, Wc, species,
                                              G, cursor, spec_packed,
                                              A, nslice, cap, words);
        int nbs = (E + SCAT_EPB - 1) / SCAT_EPB;
        scatter_kernel<<<nbs, SCAT_THREADS, 0, stream>>>(
            vecs, centers, neighbors, spec_packed, cursor, payload,
            E, nslice, cap, words);
        accum_kernel<<<nslice, ACC_THREADS, 0, stream>>>(
            payload, cursor, G, (float*)d_out, A, cap);
    } else {
        unsigned long long* vacc = (unsigned long long*)d_ws;  // (A,4)
        float* G = (float*)(vacc + (size_t)A * 4);
        unsigned int* cursor_dummy = (unsigned int*)(G + 256);
        (void)hipMemsetAsync(vacc, 0, (size_t)A * 4 * sizeof(unsigned long long), stream);
        init_kernel<<<1, 1024, 0, stream>>>(W_species, Emb, Wc, species,
                                            G, cursor_dummy, cursor_dummy,
                                            0, 0, 0, 0);
        const int threads = 256;
        edge_kernel_fb<<<(E + threads - 1) / threads, threads, 0, stream>>>(
            vecs, centers, neighbors, species, G, vacc, E);
        finalize_fb<<<(A + threads - 1) / threads, threads, 0, stream>>>(
            vacc, (float*)d_out, A);
    }
}